// Round 1
// baseline (790.959 us; speedup 1.0000x reference)
//
#include <hip/hip_runtime.h>
#include <stdint.h>
#include <stddef.h>

// Problem constants (from reference: b=8,c=16,p=512,d=1024,g=512)
#define BB 8
#define CC 16
#define PP 512
#define DD 1024
#define GG 512
#define PT 32      // p-rows per workgroup
#define BK 32      // K-chunk for both GEMMs

typedef __bf16  bfrag  __attribute__((ext_vector_type(8)));   // MFMA A/B operand (4 VGPRs)
typedef float   f32x4  __attribute__((ext_vector_type(4)));   // MFMA C/D operand
typedef short   s16x4  __attribute__((ext_vector_type(4)));
typedef short   s16x8  __attribute__((ext_vector_type(8)));

__device__ __forceinline__ short f2bf(float x) {
    // round-to-nearest-even fp32 -> bf16 (inputs are finite randn; no NaN path)
    uint32_t u = __float_as_uint(x);
    u += 0x7fffu + ((u >> 16) & 1u);
    return (short)(u >> 16);
}
__device__ __forceinline__ float bf2f(short s) {
    return __uint_as_float(((uint32_t)(uint16_t)s) << 16);
}

// ---------------------------------------------------------------------------
// Prep kernel (ws path): W fp32 [B][G][D] -> wbf bf16 [B][G][D], wt bf16 [B][D][G]
// grid: BB * (GG/32) * (DD/32) = 8*16*32 = 4096 blocks, 256 threads
// ---------------------------------------------------------------------------
__global__ __launch_bounds__(256) void w_prep(const float* __restrict__ w,
                                              short* __restrict__ wbf,
                                              short* __restrict__ wt) {
    __shared__ short T[32][33];           // +1 pad breaks transpose conflicts
    const int blk = blockIdx.x;
    const int di = blk & 31;              // DD/32 = 32
    const int gi = (blk >> 5) & 15;       // GG/32 = 16
    const int b  = blk >> 9;
    const int g0 = gi * 32, d0 = di * 32;
    const int r  = threadIdx.x >> 3;      // 0..31
    const int c4 = (threadIdx.x & 7) * 4; // 0..28

    const float4 v = *(const float4*)(w + ((size_t)(b * GG + g0 + r)) * DD + d0 + c4);
    s16x4 s;
    s.x = f2bf(v.x); s.y = f2bf(v.y); s.z = f2bf(v.z); s.w = f2bf(v.w);
    *(s16x4*)(wbf + ((size_t)(b * GG + g0 + r)) * DD + d0 + c4) = s;
    T[r][c4 + 0] = s.x; T[r][c4 + 1] = s.y; T[r][c4 + 2] = s.z; T[r][c4 + 3] = s.w;
    __syncthreads();
    s16x4 o;
    o.x = T[c4 + 0][r]; o.y = T[c4 + 1][r]; o.z = T[c4 + 2][r]; o.w = T[c4 + 3][r];
    *(s16x4*)(wt + ((size_t)(b * DD + d0 + r)) * GG + g0 + c4) = o;
}

// ---------------------------------------------------------------------------
// Fused kernel: per WG = one (b,c) and 32 p-rows.
//   Phase A: S[32x512] = Q * W^T  (bf16 MFMA, K-loop over D)
//   Phase B: relu -> Sbuf (bf16, LDS), row L1 sums -> 1/denom
//   Phase C: msg[32x1024] = Sbuf * W, scaled per-row by 1/denom in epilogue
// LDS union: phase A {Qs[32][40], Ws[512][40]} = 43520 B; phase B/C
//            {Sb[32][520] = 33280 B, rden[32] at +33280}.
// ---------------------------------------------------------------------------
template <int USE_WS>
__global__ __launch_bounds__(256, 2) void fused_topic(const float* __restrict__ qz,
                                                      const float* __restrict__ wfull,
                                                      const short* __restrict__ wbf,
                                                      const short* __restrict__ wt,
                                                      float* __restrict__ out) {
    __shared__ __align__(16) char smem[43520];
    short* Qs = (short*)smem;                 // [PT][40]
    short* Ws = (short*)smem + PT * 40;       // [GG][40]
    short* Sb = (short*)smem;                 // [PT][520]  (aliases Qs/Ws, phase B+)
    float* rden = (float*)(smem + 33280);     // [PT]

    const int tid  = threadIdx.x;
    const int wave = tid >> 6;
    const int lane = tid & 63;
    const int m    = lane & 15;
    const int quad = lane >> 4;

    const int bc = blockIdx.x >> 4;   // 0..127  (b*16+c)
    const int pt = blockIdx.x & 15;
    const int b  = bc >> 4;
    const int p0 = pt * PT;

    const float* qzb = qz + ((size_t)(bc * PP + p0)) * DD;   // Q tile [PT][DD]
    const float* wb  = wfull + (size_t)b * GG * DD;          // W_b [GG][DD]

    // ---------------- Phase A: GEMM1 ----------------
    f32x4 acc[2][8];
#pragma unroll
    for (int i = 0; i < 2; i++)
#pragma unroll
        for (int j = 0; j < 8; j++) acc[i][j] = (f32x4){0.f, 0.f, 0.f, 0.f};

    for (int kk = 0; kk < DD; kk += BK) {
        // stage Q tile [32][32] (fp32 -> bf16)
        {
            const int r = tid >> 3;
            const int c = (tid & 7) * 4;
            const float4 q = *(const float4*)(qzb + (size_t)r * DD + kk + c);
            s16x4 qs;
            qs.x = f2bf(q.x); qs.y = f2bf(q.y); qs.z = f2bf(q.z); qs.w = f2bf(q.w);
            *(s16x4*)&Qs[r * 40 + c] = qs;
        }
        // stage W tile [512][32]
        if (USE_WS) {
            const short* src = wbf + (size_t)b * GG * DD;
#pragma unroll
            for (int i = 0; i < 8; i++) {
                const int gr = tid + 256 * i;      // 16B granule id, 2048 total
                const int r = gr >> 2, q = gr & 3;
                s16x8 v = *(const s16x8*)(src + (size_t)r * DD + kk + q * 8);
                *(s16x8*)&Ws[r * 40 + q * 8] = v;
            }
        } else {
            const int c = (tid & 7) * 4;
#pragma unroll 4
            for (int i = 0; i < 16; i++) {
                const int r = (tid >> 3) + 32 * i;
                const float4 wv = *(const float4*)(wb + (size_t)r * DD + kk + c);
                s16x4 ws;
                ws.x = f2bf(wv.x); ws.y = f2bf(wv.y); ws.z = f2bf(wv.z); ws.w = f2bf(wv.w);
                *(s16x4*)&Ws[r * 40 + c] = ws;
            }
        }
        __syncthreads();

        bfrag af[2];
#pragma unroll
        for (int mt = 0; mt < 2; mt++)
            af[mt] = *(const bfrag*)&Qs[(mt * 16 + m) * 40 + quad * 8];
#pragma unroll
        for (int nt = 0; nt < 8; nt++) {
            const bfrag bf = *(const bfrag*)&Ws[(wave * 128 + nt * 16 + m) * 40 + quad * 8];
            acc[0][nt] = __builtin_amdgcn_mfma_f32_16x16x32_bf16(af[0], bf, acc[0][nt], 0, 0, 0);
            acc[1][nt] = __builtin_amdgcn_mfma_f32_16x16x32_bf16(af[1], bf, acc[1][nt], 0, 0, 0);
        }
        __syncthreads();
    }

    // ---------------- Phase B: relu -> Sbuf, row L1 sums ----------------
    // C/D layout: col = lane&15, row = quad*4 + reg  [verified m89/m91]
#pragma unroll
    for (int mt = 0; mt < 2; mt++)
#pragma unroll
        for (int nt = 0; nt < 8; nt++)
#pragma unroll
            for (int r = 0; r < 4; r++) {
                float v = acc[mt][nt][r];
                v = v > 0.f ? v : 0.f;
                const int prow = mt * 16 + quad * 4 + r;
                const int g = wave * 128 + nt * 16 + m;
                Sb[prow * 520 + g] = f2bf(v);
            }
    __syncthreads();
    {
        const int r = tid >> 3;      // row 0..31
        const int c = tid & 7;       // 8 threads per row, 64 g each
        float s = 0.f;
#pragma unroll
        for (int i = 0; i < 8; i++) {
            s16x8 v = *(const s16x8*)&Sb[r * 520 + c * 64 + i * 8];
#pragma unroll
            for (int j = 0; j < 8; j++) s += bf2f(v[j]);
        }
#pragma unroll
        for (int o = 1; o < 8; o <<= 1) s += __shfl_xor(s, o, 64);
        if (c == 0) rden[r] = 1.0f / fmaxf(s, 1e-6f);
    }
    __syncthreads();

    // ---------------- Phase C: GEMM2 ----------------
    f32x4 acc2[2][16];
#pragma unroll
    for (int i = 0; i < 2; i++)
#pragma unroll
        for (int j = 0; j < 16; j++) acc2[i][j] = (f32x4){0.f, 0.f, 0.f, 0.f};

    const int d0 = wave * 256;   // each wave owns 256 output d-columns
    for (int kk = 0; kk < GG; kk += BK) {
        bfrag af[2];
#pragma unroll
        for (int mt = 0; mt < 2; mt++)
            af[mt] = *(const bfrag*)&Sb[(mt * 16 + m) * 520 + kk + quad * 8];
#pragma unroll
        for (int nt = 0; nt < 16; nt++) {
            const int n = d0 + nt * 16 + m;
            bfrag bfr;
            if (USE_WS) {
                bfr = *(const bfrag*)(wt + ((size_t)b * DD + n) * GG + kk + quad * 8);
            } else {
                union { short s[8]; bfrag v; } u;
                const float* src = wb + (size_t)(kk + quad * 8) * DD + n;
#pragma unroll
                for (int j = 0; j < 8; j++) u.s[j] = f2bf(src[(size_t)j * DD]);
                bfr = u.v;
            }
            acc2[0][nt] = __builtin_amdgcn_mfma_f32_16x16x32_bf16(af[0], bfr, acc2[0][nt], 0, 0, 0);
            acc2[1][nt] = __builtin_amdgcn_mfma_f32_16x16x32_bf16(af[1], bfr, acc2[1][nt], 0, 0, 0);
        }
    }

    // epilogue: per-row scale by 1/denom, store fp32
    float rd[2][4];
#pragma unroll
    for (int mt = 0; mt < 2; mt++)
#pragma unroll
        for (int r = 0; r < 4; r++) rd[mt][r] = rden[mt * 16 + quad * 4 + r];
#pragma unroll
    for (int mt = 0; mt < 2; mt++)
#pragma unroll
        for (int nt = 0; nt < 16; nt++) {
            const int d = d0 + nt * 16 + m;
#pragma unroll
            for (int r = 0; r < 4; r++) {
                const int prow = mt * 16 + quad * 4 + r;
                out[((size_t)(bc * PP + p0 + prow)) * DD + d] = acc2[mt][nt][r] * rd[mt][r];
            }
        }
}

extern "C" void kernel_launch(void* const* d_in, const int* in_sizes, int n_in,
                              void* d_out, int out_size, void* d_ws, size_t ws_size,
                              hipStream_t stream) {
    const float* qz = (const float*)d_in[0];
    const float* w  = (const float*)d_in[1];
    float* out = (float*)d_out;

    const size_t wbf_elems = (size_t)BB * GG * DD;              // 4M bf16
    const size_t ws_needed = 2 * wbf_elems * sizeof(short);     // 16 MB

    if (ws_size >= ws_needed) {
        short* wbf = (short*)d_ws;
        short* wt  = wbf + wbf_elems;
        w_prep<<<dim3(BB * 16 * 32), dim3(256), 0, stream>>>(w, wbf, wt);
        fused_topic<1><<<dim3(128 * (PP / PT)), dim3(256), 0, stream>>>(qz, w, wbf, wt, out);
    } else {
        fused_topic<0><<<dim3(128 * (PP / PT)), dim3(256), 0, stream>>>(qz, w, nullptr, nullptr, out);
    }
}

// Round 2
// 613.396 us; speedup vs baseline: 1.2895x; 1.2895x over previous
//
#include <hip/hip_runtime.h>
#include <stdint.h>
#include <stddef.h>

// Problem constants (b=8,c=16,p=512,d=1024,g=512)
#define BB 8
#define CC 16
#define PP 512
#define DD 1024
#define GG 512

typedef __bf16  bfrag  __attribute__((ext_vector_type(8)));   // MFMA A/B operand
typedef float   f32x4  __attribute__((ext_vector_type(4)));   // MFMA C/D operand
typedef short   s16x4  __attribute__((ext_vector_type(4)));
typedef short   s16x8  __attribute__((ext_vector_type(8)));

__device__ __forceinline__ short f2bf(float x) {
    uint32_t u = __float_as_uint(x);
    u += 0x7fffu + ((u >> 16) & 1u);
    return (short)(u >> 16);
}
__device__ __forceinline__ float bf2f(short s) {
    return __uint_as_float(((uint32_t)(uint16_t)s) << 16);
}

// async global->LDS, 16B per lane. LDS dest must be uniform-base + lane*16.
typedef const __attribute__((address_space(1))) unsigned int* gas1_t;
typedef __attribute__((address_space(3))) unsigned int* las3_t;
__device__ __forceinline__ void gl2lds16(const void* g, void* l) {
    __builtin_amdgcn_global_load_lds((gas1_t)(uintptr_t)g,
                                     (las3_t)(uint32_t)(uintptr_t)l, 16, 0, 0);
}

// ---------------------------------------------------------------------------
// Prep: W fp32 [B][G][D] -> wbf bf16 [B][G][D], wt bf16 [B][D][G]
// ---------------------------------------------------------------------------
__global__ __launch_bounds__(256) void w_prep(const float* __restrict__ w,
                                              short* __restrict__ wbf,
                                              short* __restrict__ wt) {
    __shared__ short T[32][33];
    const int blk = blockIdx.x;
    const int di = blk & 31;
    const int gi = (blk >> 5) & 15;
    const int b  = blk >> 9;
    const int g0 = gi * 32, d0 = di * 32;
    const int r  = threadIdx.x >> 3;
    const int c4 = (threadIdx.x & 7) * 4;

    const float4 v = *(const float4*)(w + ((size_t)(b * GG + g0 + r)) * DD + d0 + c4);
    s16x4 s;
    s.x = f2bf(v.x); s.y = f2bf(v.y); s.z = f2bf(v.z); s.w = f2bf(v.w);
    *(s16x4*)(wbf + ((size_t)(b * GG + g0 + r)) * DD + d0 + c4) = s;
    T[r][c4 + 0] = s.x; T[r][c4 + 1] = s.y; T[r][c4 + 2] = s.z; T[r][c4 + 3] = s.w;
    __syncthreads();
    s16x4 o;
    o.x = T[c4 + 0][r]; o.y = T[c4 + 1][r]; o.z = T[c4 + 2][r]; o.w = T[c4 + 3][r];
    *(s16x4*)(wt + ((size_t)(b * DD + d0 + r)) * GG + g0 + c4) = o;
}

// ---------------------------------------------------------------------------
// gemm1n: qg[row0..row0+63][0..511] = normalize(relu(qz . W^T))  (bf16 out)
// Tile 64(M) x 512(N=full g) x K=1024, BK=32, 256 threads, grid 1024.
// LDS: As[64][32] (4KB) + Bs[512][32] (32KB), unpadded (global_load_lds).
// ---------------------------------------------------------------------------
__global__ __launch_bounds__(256, 2) void gemm1n(const float* __restrict__ qz,
                                                 const short* __restrict__ wbf,
                                                 short* __restrict__ qg) {
    __shared__ __align__(16) char smem[36864];
    short* As = (short*)smem;              // [64][32]
    short* Bs = (short*)(smem + 4096);     // [512][32]
    float* red  = (float*)smem;            // [4][64]  (reused after K-loop)
    float* rden = (float*)(smem + 2048);   // [64]

    const int tid  = threadIdx.x;
    const int wave = tid >> 6;
    const int lane = tid & 63;
    const int m    = lane & 15;
    const int quad = lane >> 4;

    const int row0 = blockIdx.x * 64;          // global p-row base (b*c*p flat)
    const int b    = row0 >> 13;               // 8192 rows per b
    const float* qrow = qz + (size_t)row0 * DD;
    const short* wb   = wbf + (size_t)b * GG * DD;

    f32x4 acc[4][8];
#pragma unroll
    for (int i = 0; i < 4; i++)
#pragma unroll
        for (int j = 0; j < 8; j++) acc[i][j] = (f32x4){0.f, 0.f, 0.f, 0.f};

    for (int kk = 0; kk < DD; kk += 32) {
        // B tile [512][32] async: 2048 granules of 16B
#pragma unroll
        for (int i = 0; i < 8; i++) {
            const int gr = tid + 256 * i;
            const int r = gr >> 2, pa = gr & 3;
            gl2lds16(wb + (size_t)r * DD + kk + pa * 8, Bs + gr * 8);
        }
        // A tile [64][32]: fp32 load + convert (qz is fp32)
#pragma unroll
        for (int i = 0; i < 2; i++) {
            const int idx = tid + 256 * i;
            const int r = idx >> 3, c = (idx & 7) * 4;
            const float4 q = *(const float4*)(qrow + (size_t)r * DD + kk + c);
            s16x4 s;
            s.x = f2bf(q.x); s.y = f2bf(q.y); s.z = f2bf(q.z); s.w = f2bf(q.w);
            *(s16x4*)&As[r * 32 + c] = s;
        }
        __syncthreads();

        bfrag af[4];
#pragma unroll
        for (int mt = 0; mt < 4; mt++)
            af[mt] = *(const bfrag*)&As[(mt * 16 + m) * 32 + quad * 8];
#pragma unroll
        for (int nt = 0; nt < 8; nt++) {
            const bfrag bf = *(const bfrag*)&Bs[(wave * 128 + nt * 16 + m) * 32 + quad * 8];
#pragma unroll
            for (int mt = 0; mt < 4; mt++)
                acc[mt][nt] = __builtin_amdgcn_mfma_f32_16x16x32_bf16(af[mt], bf, acc[mt][nt], 0, 0, 0);
        }
        __syncthreads();
    }

    // relu + fp32 row sums (cols of this wave: wave*128 .. +127)
    float part[4][4];
#pragma unroll
    for (int mt = 0; mt < 4; mt++)
#pragma unroll
        for (int r = 0; r < 4; r++) part[mt][r] = 0.f;
#pragma unroll
    for (int mt = 0; mt < 4; mt++)
#pragma unroll
        for (int nt = 0; nt < 8; nt++)
#pragma unroll
            for (int r = 0; r < 4; r++) {
                float v = fmaxf(acc[mt][nt][r], 0.f);
                acc[mt][nt][r] = v;
                part[mt][r] += v;
            }
#pragma unroll
    for (int o = 1; o < 16; o <<= 1)
#pragma unroll
        for (int mt = 0; mt < 4; mt++)
#pragma unroll
            for (int r = 0; r < 4; r++) part[mt][r] += __shfl_xor(part[mt][r], o, 64);
    if (m == 0)
#pragma unroll
        for (int mt = 0; mt < 4; mt++)
#pragma unroll
            for (int r = 0; r < 4; r++)
                red[wave * 64 + mt * 16 + quad * 4 + r] = part[mt][r];
    __syncthreads();
    if (tid < 64) {
        const float s = red[tid] + red[64 + tid] + red[128 + tid] + red[192 + tid];
        rden[tid] = 1.0f / fmaxf(s, 1e-6f);
    }
    __syncthreads();

    float rd[4][4];
#pragma unroll
    for (int mt = 0; mt < 4; mt++)
#pragma unroll
        for (int r = 0; r < 4; r++) rd[mt][r] = rden[mt * 16 + quad * 4 + r];
#pragma unroll
    for (int mt = 0; mt < 4; mt++)
#pragma unroll
        for (int nt = 0; nt < 8; nt++) {
            const int col = wave * 128 + nt * 16 + m;
#pragma unroll
            for (int r = 0; r < 4; r++) {
                const int row = mt * 16 + quad * 4 + r;
                qg[(size_t)(row0 + row) * GG + col] = f2bf(acc[mt][nt][r] * rd[mt][r]);
            }
        }
}

// ---------------------------------------------------------------------------
// gemm2: out[row][d] = qg[row][g] . wt[b][d][g]   (fp32 out, qg pre-normalized)
// 128x128 tile, K=512, BK=32, 256 threads, grid 512*8 = 4096.
// ---------------------------------------------------------------------------
__global__ __launch_bounds__(256, 4) void gemm2(const short* __restrict__ qg,
                                                const short* __restrict__ wt,
                                                float* __restrict__ out) {
    __shared__ __align__(16) char smem[16384];
    short* As = (short*)smem;              // [128][32]
    short* Bs = (short*)(smem + 8192);     // [128][32]

    const int tid  = threadIdx.x;
    const int wave = tid >> 6;
    const int lane = tid & 63;
    const int m    = lane & 15;
    const int quad = lane >> 4;

    const int nt8   = blockIdx.x & 7;          // d-tile
    const int mt512 = blockIdx.x >> 3;         // p-row tile, 0..511
    const int row0  = mt512 * 128;
    const int b     = row0 >> 13;
    const int d0    = nt8 * 128;
    const short* arow = qg + (size_t)row0 * GG;
    const short* brow = wt + ((size_t)b * DD + d0) * GG;
    const int r0 = (wave >> 1) * 64;           // wave's 64 rows
    const int c0 = (wave & 1) * 64;            // wave's 64 cols

    f32x4 acc[4][4];
#pragma unroll
    for (int i = 0; i < 4; i++)
#pragma unroll
        for (int j = 0; j < 4; j++) acc[i][j] = (f32x4){0.f, 0.f, 0.f, 0.f};

    for (int kk = 0; kk < GG; kk += 32) {
#pragma unroll
        for (int i = 0; i < 2; i++) {
            const int gr = tid + 256 * i;
            const int r = gr >> 2, pa = gr & 3;
            gl2lds16(arow + (size_t)r * GG + kk + pa * 8, As + gr * 8);
            gl2lds16(brow + (size_t)r * GG + kk + pa * 8, Bs + gr * 8);
        }
        __syncthreads();

        bfrag af[4];
#pragma unroll
        for (int mt = 0; mt < 4; mt++)
            af[mt] = *(const bfrag*)&As[(r0 + mt * 16 + m) * 32 + quad * 8];
#pragma unroll
        for (int nt = 0; nt < 4; nt++) {
            const bfrag bf = *(const bfrag*)&Bs[(c0 + nt * 16 + m) * 32 + quad * 8];
#pragma unroll
            for (int mt = 0; mt < 4; mt++)
                acc[mt][nt] = __builtin_amdgcn_mfma_f32_16x16x32_bf16(af[mt], bf, acc[mt][nt], 0, 0, 0);
        }
        __syncthreads();
    }

#pragma unroll
    for (int mt = 0; mt < 4; mt++)
#pragma unroll
        for (int nt = 0; nt < 4; nt++) {
            const int d = d0 + c0 + nt * 16 + m;
#pragma unroll
            for (int r = 0; r < 4; r++) {
                const int row = row0 + r0 + mt * 16 + quad * 4 + r;
                out[(size_t)row * DD + d] = acc[mt][nt][r];
            }
        }
}

// ---------------------------------------------------------------------------
// Fallback: round-1 fused kernel (used when ws is too small for the 3-kernel
// pipeline). Proven correct at absmax 1.95e-3.
// ---------------------------------------------------------------------------
template <int USE_WS>
__global__ __launch_bounds__(256, 2) void fused_topic(const float* __restrict__ qz,
                                                      const float* __restrict__ wfull,
                                                      const short* __restrict__ wbf,
                                                      const short* __restrict__ wt,
                                                      float* __restrict__ out) {
    __shared__ __align__(16) char smem[43520];
    short* Qs = (short*)smem;
    short* Ws = (short*)smem + 32 * 40;
    short* Sb = (short*)smem;
    float* rden = (float*)(smem + 33280);

    const int tid  = threadIdx.x;
    const int wave = tid >> 6;
    const int lane = tid & 63;
    const int m    = lane & 15;
    const int quad = lane >> 4;

    const int bc = blockIdx.x >> 4;
    const int pt = blockIdx.x & 15;
    const int b  = bc >> 4;
    const int p0 = pt * 32;

    const float* qzb = qz + ((size_t)(bc * PP + p0)) * DD;
    const float* wb  = wfull + (size_t)b * GG * DD;

    f32x4 acc[2][8];
#pragma unroll
    for (int i = 0; i < 2; i++)
#pragma unroll
        for (int j = 0; j < 8; j++) acc[i][j] = (f32x4){0.f, 0.f, 0.f, 0.f};

    for (int kk = 0; kk < DD; kk += 32) {
        {
            const int r = tid >> 3;
            const int c = (tid & 7) * 4;
            const float4 q = *(const float4*)(qzb + (size_t)r * DD + kk + c);
            s16x4 qs;
            qs.x = f2bf(q.x); qs.y = f2bf(q.y); qs.z = f2bf(q.z); qs.w = f2bf(q.w);
            *(s16x4*)&Qs[r * 40 + c] = qs;
        }
        if (USE_WS) {
            const short* src = wbf + (size_t)b * GG * DD;
#pragma unroll
            for (int i = 0; i < 8; i++) {
                const int gr = tid + 256 * i;
                const int r = gr >> 2, q = gr & 3;
                s16x8 v = *(const s16x8*)(src + (size_t)r * DD + kk + q * 8);
                *(s16x8*)&Ws[r * 40 + q * 8] = v;
            }
        } else {
            const int c = (tid & 7) * 4;
#pragma unroll 4
            for (int i = 0; i < 16; i++) {
                const int r = (tid >> 3) + 32 * i;
                const float4 wv = *(const float4*)(wb + (size_t)r * DD + kk + c);
                s16x4 ws;
                ws.x = f2bf(wv.x); ws.y = f2bf(wv.y); ws.z = f2bf(wv.z); ws.w = f2bf(wv.w);
                *(s16x4*)&Ws[r * 40 + c] = ws;
            }
        }
        __syncthreads();

        bfrag af[2];
#pragma unroll
        for (int mt = 0; mt < 2; mt++)
            af[mt] = *(const bfrag*)&Qs[(mt * 16 + m) * 40 + quad * 8];
#pragma unroll
        for (int nt = 0; nt < 8; nt++) {
            const bfrag bf = *(const bfrag*)&Ws[(wave * 128 + nt * 16 + m) * 40 + quad * 8];
            acc[0][nt] = __builtin_amdgcn_mfma_f32_16x16x32_bf16(af[0], bf, acc[0][nt], 0, 0, 0);
            acc[1][nt] = __builtin_amdgcn_mfma_f32_16x16x32_bf16(af[1], bf, acc[1][nt], 0, 0, 0);
        }
        __syncthreads();
    }

#pragma unroll
    for (int mt = 0; mt < 2; mt++)
#pragma unroll
        for (int nt = 0; nt < 8; nt++)
#pragma unroll
            for (int r = 0; r < 4; r++) {
                float v = acc[mt][nt][r];
                v = v > 0.f ? v : 0.f;
                const int prow = mt * 16 + quad * 4 + r;
                const int g = wave * 128 + nt * 16 + m;
                Sb[prow * 520 + g] = f2bf(v);
            }
    __syncthreads();
    {
        const int r = tid >> 3;
        const int c = tid & 7;
        float s = 0.f;
#pragma unroll
        for (int i = 0; i < 8; i++) {
            s16x8 v = *(const s16x8*)&Sb[r * 520 + c * 64 + i * 8];
#pragma unroll
            for (int j = 0; j < 8; j++) s += bf2f(v[j]);
        }
#pragma unroll
        for (int o = 1; o < 8; o <<= 1) s += __shfl_xor(s, o, 64);
        if (c == 0) rden[r] = 1.0f / fmaxf(s, 1e-6f);
    }
    __syncthreads();

    f32x4 acc2[2][16];
#pragma unroll
    for (int i = 0; i < 2; i++)
#pragma unroll
        for (int j = 0; j < 16; j++) acc2[i][j] = (f32x4){0.f, 0.f, 0.f, 0.f};

    const int d0 = wave * 256;
    for (int kk = 0; kk < GG; kk += 32) {
        bfrag af[2];
#pragma unroll
        for (int mt = 0; mt < 2; mt++)
            af[mt] = *(const bfrag*)&Sb[(mt * 16 + m) * 520 + kk + quad * 8];
#pragma unroll
        for (int nt = 0; nt < 16; nt++) {
            const int n = d0 + nt * 16 + m;
            bfrag bfr;
            if (USE_WS) {
                bfr = *(const bfrag*)(wt + ((size_t)b * DD + n) * GG + kk + quad * 8);
            } else {
                union { short s[8]; bfrag v; } u;
                const float* src = wb + (size_t)(kk + quad * 8) * DD + n;
#pragma unroll
                for (int j = 0; j < 8; j++) u.s[j] = f2bf(src[(size_t)j * DD]);
                bfr = u.v;
            }
            acc2[0][nt] = __builtin_amdgcn_mfma_f32_16x16x32_bf16(af[0], bfr, acc2[0][nt], 0, 0, 0);
            acc2[1][nt] = __builtin_amdgcn_mfma_f32_16x16x32_bf16(af[1], bfr, acc2[1][nt], 0, 0, 0);
        }
    }

    float rd[2][4];
#pragma unroll
    for (int mt = 0; mt < 2; mt++)
#pragma unroll
        for (int r = 0; r < 4; r++) rd[mt][r] = rden[mt * 16 + quad * 4 + r];
#pragma unroll
    for (int mt = 0; mt < 2; mt++)
#pragma unroll
        for (int nt = 0; nt < 16; nt++) {
            const int d = d0 + nt * 16 + m;
#pragma unroll
            for (int r = 0; r < 4; r++) {
                const int prow = mt * 16 + quad * 4 + r;
                out[((size_t)(bc * PP + p0 + prow)) * DD + d] = acc2[mt][nt][r] * rd[mt][r];
            }
        }
}

extern "C" void kernel_launch(void* const* d_in, const int* in_sizes, int n_in,
                              void* d_out, int out_size, void* d_ws, size_t ws_size,
                              hipStream_t stream) {
    const float* qz = (const float*)d_in[0];
    const float* w  = (const float*)d_in[1];
    float* out = (float*)d_out;

    const size_t wbf_elems = (size_t)BB * GG * DD;                  // 4M
    const size_t qg_elems  = (size_t)BB * CC * PP * GG;             // 32M
    const size_t ws_full   = (2 * wbf_elems + qg_elems) * sizeof(short); // 80 MB
    const size_t ws_old    = 2 * wbf_elems * sizeof(short);             // 16 MB

    if (ws_size >= ws_full) {
        short* wbf = (short*)d_ws;
        short* wt  = wbf + wbf_elems;
        short* qg  = wt + wbf_elems;
        w_prep<<<dim3(BB * 16 * 32), dim3(256), 0, stream>>>(w, wbf, wt);
        gemm1n<<<dim3((BB * CC * PP) / 64), dim3(256), 0, stream>>>(qz, wbf, qg);
        gemm2<<<dim3(((BB * CC * PP) / 128) * (DD / 128)), dim3(256), 0, stream>>>(qg, wt, out);
    } else if (ws_size >= ws_old) {
        short* wbf = (short*)d_ws;
        short* wt  = wbf + wbf_elems;
        w_prep<<<dim3(BB * 16 * 32), dim3(256), 0, stream>>>(w, wbf, wt);
        fused_topic<1><<<dim3(128 * 16), dim3(256), 0, stream>>>(qz, w, wbf, wt, out);
    } else {
        fused_topic<0><<<dim3(128 * 16), dim3(256), 0, stream>>>(qz, w, nullptr, nullptr, out);
    }
}